// Round 6
// baseline (27.185 us; speedup 1.0000x reference)
//
#include <hip/hip_runtime.h>
#include <math.h>

// FRN projection head, MI355X — single fused kernel, R6.
// Math: hat = (StS+lam I)^-1 StS = I - lam*Minv ; B = rho*hat - I (symmetric)
//       G = B^2 ; neg_l2[img,n] = -(1/100) <G_n, C_img>,  C_img = A A^T (Gram)
// Minv via Gershgorin-bounded Chebyshev-1 init + 2 Newton-Schulz iterations.
// R6 layout (grid 305 x 256, 54KB LDS -> 2 blk/CU -> 512 slots >= 305: safe):
//  - b 0..74  : support Grams, 2 imgs, 4-wave k-split (k-chunks additive)
//  - b 75..79 : dedicated per-class solve (sum 15 partials, NS) -> packed G
//  - b 80..304: query, 2 imgs, 2-wave k-split/img, partial-dot + pair reduce
//  - b 80     : gathers 225 per-block loss partials (fixed order)
// Sync: R5's proven relaxed-poll + single acquire fence; release fence + flag.

typedef __attribute__((ext_vector_type(8))) short short8;   // 8 x bf16 bits
typedef __attribute__((ext_vector_type(4))) float f32x4;

#define NSUP 150
#define NQ 450
#define PIX 100
#define IMG_STRIDE 6400   // 64*100 floats per image
#define MAGIC 0x5F3D2B1Cu

static __device__ __forceinline__ short bf16r(float x) {   // f32 -> bf16 (RNE)
  unsigned u = __builtin_bit_cast(unsigned, x);
  u += 0x7FFFu + ((u >> 16) & 1u);
  return (short)(u >> 16);
}
static __device__ __forceinline__ float b2f(short v) {
  return __builtin_bit_cast(float, ((unsigned)(unsigned short)v) << 16);
}
// producer: one agent release fence (writeback), then relaxed flag store.
static __device__ __forceinline__ void st_flag(unsigned* p, unsigned v) {
  __builtin_amdgcn_fence(__ATOMIC_RELEASE, "agent");
  __hip_atomic_store(p, v, __ATOMIC_RELAXED, __HIP_MEMORY_SCOPE_AGENT);
}
// consumer poll: relaxed (no per-poll invalidate); caller fences ACQUIRE after.
static __device__ __forceinline__ void spin_rlx(unsigned* p) {
  int guard = 1 << 22;
  while (__hip_atomic_load(p, __ATOMIC_RELAXED, __HIP_MEMORY_SCOPE_AGENT) != MAGIC
         && --guard) __builtin_amdgcn_s_sleep(2);
}

// One k-chunk (32 of 128, zero-padded past 100) of acc += A*A^T, direct global.
// C/D layout: row = R*16 + (lane>>4)*4 + q, col = C*16 + (lane&15).
static __device__ __forceinline__ void gram_ks(const float* __restrict__ f,
                                               f32x4 acc[4][4], int ks, int r, int g) {
  short8 frag[4];
  const int kb = ks * 32 + g * 8;
  #pragma unroll
  for (int R = 0; R < 4; ++R) {
    short8 q;
    const float* p = f + (R * 16 + r) * PIX + kb;
    if (ks < 3) {
      float4 lo = *(const float4*)p;
      float4 hi = *(const float4*)(p + 4);
      q[0] = bf16r(lo.x); q[1] = bf16r(lo.y); q[2] = bf16r(lo.z); q[3] = bf16r(lo.w);
      q[4] = bf16r(hi.x); q[5] = bf16r(hi.y); q[6] = bf16r(hi.z); q[7] = bf16r(hi.w);
    } else if (g == 0) {                   // k = 96..99 valid, rest zero-pad
      float4 lo = *(const float4*)p;
      q[0] = bf16r(lo.x); q[1] = bf16r(lo.y); q[2] = bf16r(lo.z); q[3] = bf16r(lo.w);
      q[4] = 0; q[5] = 0; q[6] = 0; q[7] = 0;
    } else {
      #pragma unroll
      for (int j = 0; j < 8; ++j) q[j] = 0;
    }
    frag[R] = q;
  }
  #pragma unroll
  for (int R = 0; R < 4; ++R)
    #pragma unroll
    for (int C = 0; C < 4; ++C)
      acc[R][C] = __builtin_amdgcn_mfma_f32_16x16x32_bf16(frag[R], frag[C],
                                                          acc[R][C], 0, 0, 0);
}

// Quadrant (wr,wc) of D = A*B for 64x64 bf16 LDS matrices (stride 72).
// B must be SYMMETRIC (B-fragment gathered as rows of B).
static __device__ __forceinline__ void mm64q(const short* A, const short* B,
                                             f32x4 t[2][2], int r, int g,
                                             int wr, int wc) {
  #pragma unroll
  for (int ks = 0; ks < 2; ++ks) {
    short8 af[2], bfr[2];
    #pragma unroll
    for (int i = 0; i < 2; ++i) {
      af[i]  = *(const short8*)(A + (wr * 32 + i * 16 + r) * 72 + ks * 32 + g * 8);
      bfr[i] = *(const short8*)(B + (wc * 32 + i * 16 + r) * 72 + ks * 32 + g * 8);
    }
    #pragma unroll
    for (int i = 0; i < 2; ++i)
      #pragma unroll
      for (int j = 0; j < 2; ++j)
        t[i][j] = __builtin_amdgcn_mfma_f32_16x16x32_bf16(af[i], bfr[j],
                                                          t[i][j], 0, 0, 0);
  }
}

#define ZERO_ACC4(t)                                  \
  _Pragma("unroll") for (int R = 0; R < 4; ++R)       \
  _Pragma("unroll") for (int C = 0; C < 4; ++C)       \
  _Pragma("unroll") for (int q = 0; q < 4; ++q) t[R][C][q] = 0.f;

#define ZERO_ACC2(t)                                  \
  _Pragma("unroll") for (int R = 0; R < 2; ++R)       \
  _Pragma("unroll") for (int C = 0; C < 2; ++C)       \
  _Pragma("unroll") for (int q = 0; q < 4; ++q) t[R][C][q] = 0.f;

__global__ __launch_bounds__(256) void k_fused(
    const float* __restrict__ feat, const int* __restrict__ label,
    const float* __restrict__ scale, const float* __restrict__ rvec,
    float* __restrict__ out,
    float* __restrict__ partial,            // 75*4096 f32
    unsigned short* __restrict__ G01h,      // 4096 x {n0,n1} packed bf16
    unsigned short* __restrict__ G23h,      // 4096 x {n2,n3}
    unsigned short* __restrict__ G4h,       // 4096 x {n4}
    float* __restrict__ blockloss,          // 225 f32
    unsigned* __restrict__ gflag,           // 75
    unsigned* __restrict__ sflag,           // 5
    unsigned* __restrict__ lflag) {         // 225
  __shared__ __align__(16) char smem[55296];
  const int b = blockIdx.x, tid = threadIdx.x;
  const int wave = tid >> 6, lane = tid & 63;
  const int r = lane & 15, g = lane >> 4;

  if (b < 75) {
    // ===== support-Gram partial: class b/15, imgs (b%15)*2 .. +1, k-split ====
    float (*sbuf)[4096] = (float (*)[4096])smem;   // 3 x 16 KB
    const int cls = b / 15, grp = b % 15;
    const float* f0 = feat + (size_t)(cls * 30 + grp * 2) * IMG_STRIDE;
    f32x4 acc[4][4];
    ZERO_ACC4(acc)
    gram_ks(f0, acc, wave, r, g);               // wave w owns k-chunk w
    gram_ks(f0 + IMG_STRIDE, acc, wave, r, g);

    if (wave) {                                  // waves 1..3 -> LDS
      #pragma unroll
      for (int R = 0; R < 4; ++R)
        #pragma unroll
        for (int C = 0; C < 4; ++C)
          #pragma unroll
          for (int q = 0; q < 4; ++q) {
            const int row = R * 16 + g * 4 + q, col = C * 16 + r;
            sbuf[wave - 1][row * 64 + col] = acc[R][C][q];
          }
    }
    __syncthreads();
    if (!wave) {                                 // wave 0 adds in-place
      #pragma unroll
      for (int R = 0; R < 4; ++R)
        #pragma unroll
        for (int C = 0; C < 4; ++C)
          #pragma unroll
          for (int q = 0; q < 4; ++q) {
            const int row = R * 16 + g * 4 + q, col = C * 16 + r;
            sbuf[0][row * 64 + col] += acc[R][C][q];
          }
    }
    __syncthreads();
    float* outp = partial + (size_t)b * 4096;
    for (int c = tid; c < 1024; c += 256) {
      f32x4 s0 = *(const f32x4*)&sbuf[0][4 * c];
      f32x4 s1 = *(const f32x4*)&sbuf[1][4 * c];
      f32x4 s2 = *(const f32x4*)&sbuf[2][4 * c];
      f32x4 s = s0 + s1 + s2;
      *(float4*)(outp + 4 * c) = *(float4*)&s;
    }
    __syncthreads();                             // all waves' stores drained
    if (tid == 0) st_flag(&gflag[b], MAGIC);
    return;
  }

  if (b < 80) {
    // ======================= per-class solve (class n) ======================
    float* Ms   = (float*)(smem);            // 64*65 f32
    short* Mb   = (short*)(smem + 16640);    // 64*72 bf16
    short* Tb   = (short*)(smem + 25856);
    short* Xa   = (short*)(smem + 35072);
    short* Xc   = (short*)(smem + 44288);
    float* radp = (float*)(smem + 53504);    // [4][64]
    float* scal = (float*)(smem + 54528);    // sS, sTheta

    const int n = b - 75;
    const int wr = wave >> 1, wc = wave & 1;
    const float lam = 46.875f * expf(rvec[0]);   // reg = 3000/64
    const float rho = expf(rvec[1]);

    if (tid < 15) spin_rlx(&gflag[n * 15 + tid]);
    __syncthreads();
    __builtin_amdgcn_fence(__ATOMIC_ACQUIRE, "agent");

    {  // M = (1/64) * sum of 15 partials (ILP) ; + lam on diag
      const float* base = partial + (size_t)n * 15 * 4096;
      for (int c = tid; c < 1024; c += 256) {
        float4 s = {0.f, 0.f, 0.f, 0.f};
        #pragma unroll
        for (int p = 0; p < 15; ++p) {
          float4 v = *(const float4*)(base + p * 4096 + 4 * c);
          s.x += v.x; s.y += v.y; s.z += v.z; s.w += v.w;
        }
        const int e = 4 * c, row = e >> 6, col = e & 63;
        Ms[row * 65 + col + 0] = s.x * (1.f / 64.f);
        Ms[row * 65 + col + 1] = s.y * (1.f / 64.f);
        Ms[row * 65 + col + 2] = s.z * (1.f / 64.f);
        Ms[row * 65 + col + 3] = s.w * (1.f / 64.f);
      }
    }
    __syncthreads();
    if (tid < 64) Ms[tid * 65 + tid] += lam;
    __syncthreads();

    {  // Gershgorin (4 threads/row) -> Chebyshev-1 init params
      const int row = tid & 63, part = tid >> 6;
      float s = 0.f;
      #pragma unroll
      for (int k = 0; k < 16; ++k) s += fabsf(Ms[row * 65 + part * 16 + k]);
      radp[part * 64 + row] = s;
    }
    __syncthreads();
    if (tid < 64) {
      const float diag = Ms[tid * 65 + tid];
      const float rad = radp[tid] + radp[64 + tid] + radp[128 + tid] +
                        radp[192 + tid] - fabsf(diag);
      float lo = diag - rad, hi = diag + rad;
      for (int off = 32; off; off >>= 1) {
        lo = fminf(lo, __shfl_down(lo, off));
        hi = fmaxf(hi, __shfl_down(hi, off));
      }
      if (tid == 0) {
        const float a = fmaxf(lo, lam);   // spectrum >= lam (StS is PSD)
        const float bb = hi;
        const float s = a + bb, d = bb - a;
        scal[0] = s;
        scal[1] = 8.f / (2.f * s * s - d * d);   // X0 = theta*(s*I - M)
      }
    }
    __syncthreads();
    const float s0 = scal[0], theta = scal[1];

    for (int e = tid; e < 4096; e += 256) {      // Mb, X0
      const int i = e >> 6, j = e & 63;
      const float m = Ms[i * 65 + j];
      Mb[i * 72 + j] = bf16r(m);
      Xa[i * 72 + j] = bf16r(theta * (((i == j) ? s0 : 0.f) - m));
    }
    __syncthreads();

    short* x = Xa;                               // 2 Newton-Schulz iterations
    short* xn = Xc;
    for (int it = 0; it < 2; ++it) {
      {
        f32x4 t[2][2];
        ZERO_ACC2(t)
        mm64q(x, Mb, t, r, g, wr, wc);           // T = X*M (M symmetric)
        #pragma unroll
        for (int i = 0; i < 2; ++i)
          #pragma unroll
          for (int j = 0; j < 2; ++j)
            #pragma unroll
            for (int q = 0; q < 4; ++q) {
              const int row = wr * 32 + i * 16 + g * 4 + q;
              const int col = wc * 32 + j * 16 + r;
              Tb[row * 72 + col] = bf16r(t[i][j][q]);
            }
      }
      __syncthreads();
      {
        f32x4 t[2][2];
        ZERO_ACC2(t)
        mm64q(Tb, x, t, r, g, wr, wc);           // T*X (X ~symmetric)
        #pragma unroll
        for (int i = 0; i < 2; ++i)
          #pragma unroll
          for (int j = 0; j < 2; ++j)
            #pragma unroll
            for (int q = 0; q < 4; ++q) {
              const int row = wr * 32 + i * 16 + g * 4 + q;
              const int col = wc * 32 + j * 16 + r;
              const int idx = row * 72 + col;
              xn[idx] = bf16r(2.f * b2f(x[idx]) - t[i][j][q]);
            }
      }
      __syncthreads();
      short* tmp = x; x = xn; xn = tmp;
    }

    for (int e = tid; e < 4096; e += 256) {      // B = (rho-1)I - rho*lam*X
      const int i = e >> 6, j = e & 63;
      const float xv = b2f(x[i * 72 + j]);
      Tb[i * 72 + j] = bf16r(((i == j) ? (rho - 1.f) : 0.f) - rho * lam * xv);
    }
    __syncthreads();

    {  // G = B*B ; store packed bf16(-G/100): n0,n1->G01  n2,n3->G23  n4->G4
      f32x4 t[2][2];
      ZERO_ACC2(t)
      mm64q(Tb, Tb, t, r, g, wr, wc);
      unsigned short* baseh = (n < 2) ? G01h : (n < 4) ? G23h : G4h;
      const int off = (n < 4) ? (n & 1) : 0;
      const int mul = (n < 4) ? 2 : 1;
      #pragma unroll
      for (int i = 0; i < 2; ++i)
        #pragma unroll
        for (int j = 0; j < 2; ++j)
          #pragma unroll
          for (int q = 0; q < 4; ++q) {
            const int row = wr * 32 + i * 16 + g * 4 + q;
            const int col = wc * 32 + j * 16 + r;
            baseh[(row * 64 + col) * mul + off] =
                (unsigned short)bf16r(t[i][j][q] * (-0.01f));
          }
    }
    __syncthreads();
    if (tid == 0) st_flag(&sflag[n], MAGIC);
    return;
  }

  // ===== query: 2 imgs/block; waves {0,1}->img A, {2,3}->img B, k-split =====
  const int qb = b - 80;                   // 0..224
  const int half = wave >> 1;
  const int gimg = qb * 2 + half;          // 0..449
  const float* fq = feat + (size_t)(NSUP + gimg) * IMG_STRIDE;
  f32x4 acc[4][4];
  ZERO_ACC4(acc)
  const int ksb = (wave & 1) * 2;          // even wave: ks 0,1 ; odd: ks 2,3
  gram_ks(fq, acc, ksb, r, g);             // overlaps the solve
  gram_ks(fq, acc, ksb + 1, r, g);

  if (tid == 0) {                          // low-traffic combined poll
    int guard = 1 << 20;
    for (;;) {
      unsigned x = 0;
      #pragma unroll
      for (int i = 0; i < 5; ++i)
        x |= __hip_atomic_load(&sflag[i], __ATOMIC_RELAXED,
                               __HIP_MEMORY_SCOPE_AGENT) ^ MAGIC;
      if (x == 0 || --guard == 0) break;
      __builtin_amdgcn_s_sleep(4);
    }
  }
  __syncthreads();
  __builtin_amdgcn_fence(__ATOMIC_ACQUIRE, "agent");

  // stage packed G into LDS, row stride 68 (2-way bank alias = free)
  unsigned*       G01s = (unsigned*)smem;                 // 64*68 u32 = 17408 B
  unsigned*       G23s = (unsigned*)(smem + 17408);       // 17408 B
  unsigned short* G4s  = (unsigned short*)(smem + 34816); // 64*68 u16 = 8704 B
  {
    const unsigned* G01w = (const unsigned*)G01h;
    const unsigned* G23w = (const unsigned*)G23h;
    for (int e = tid; e < 4096; e += 256) {
      const int row = e >> 6, col = e & 63;
      G01s[row * 68 + col] = G01w[e];
      G23s[row * 68 + col] = G23w[e];
    }
    const unsigned* G4w = (const unsigned*)G4h;
    unsigned* G4sw = (unsigned*)G4s;
    for (int e = tid; e < 2048; e += 256) {
      const int row = e >> 5, cw = e & 31;
      G4sw[row * 34 + cw] = G4w[e];
    }
  }
  __syncthreads();

  float nl[5] = {0.f, 0.f, 0.f, 0.f, 0.f};   // partial <Gneg_n, C> (this k-half)
  #pragma unroll
  for (int R = 0; R < 4; ++R)
    #pragma unroll
    for (int C = 0; C < 4; ++C)
      #pragma unroll
      for (int q = 0; q < 4; ++q) {
        const int row = R * 16 + g * 4 + q, col = C * 16 + r;
        const float cv = acc[R][C][q] * (1.f / 64.f);
        const int i68 = row * 68 + col;
        const unsigned v01 = G01s[i68], v23 = G23s[i68];
        nl[0] += b2f((short)(v01 & 0xffff)) * cv;
        nl[1] += b2f((short)(v01 >> 16)) * cv;
        nl[2] += b2f((short)(v23 & 0xffff)) * cv;
        nl[3] += b2f((short)(v23 >> 16)) * cv;
        nl[4] += b2f((short)G4s[i68]) * cv;
      }
  #pragma unroll
  for (int nn = 0; nn < 5; ++nn)
    for (int off = 32; off; off >>= 1) nl[nn] += __shfl_down(nl[nn], off);

  float* wl  = (float*)(smem + 43520);     // [4][5] wave partials
  float* wl2 = (float*)(smem + 43600);     // [2] per-image losses
  if (lane == 0) {
    #pragma unroll
    for (int nn = 0; nn < 5; ++nn) wl[wave * 5 + nn] = nl[nn];
  }
  __syncthreads();
  if ((wave & 1) == 0 && lane == 0) {      // wave 0 -> img A, wave 2 -> img B
    float nlf[5];
    #pragma unroll
    for (int nn = 0; nn < 5; ++nn)
      nlf[nn] = wl[wave * 5 + nn] + wl[(wave + 1) * 5 + nn];

    float mx = nlf[0];
    #pragma unroll
    for (int nn = 1; nn < 5; ++nn) mx = fmaxf(mx, nlf[nn]);
    float ex[5], se = 0.f;
    #pragma unroll
    for (int nn = 0; nn < 5; ++nn) { ex[nn] = expf(nlf[nn] - mx); se += ex[nn]; }
    const float inv = 1.f / se;
    #pragma unroll
    for (int nn = 0; nn < 5; ++nn) out[gimg * 5 + nn] = ex[nn] * inv;

    const float sc = scale[0];
    float mx2 = nlf[0] * sc;
    #pragma unroll
    for (int nn = 1; nn < 5; ++nn) mx2 = fmaxf(mx2, nlf[nn] * sc);
    float se2 = 0.f;
    #pragma unroll
    for (int nn = 0; nn < 5; ++nn) se2 += expf(nlf[nn] * sc - mx2);
    wl2[half] = mx2 + logf(se2) - nlf[label[gimg]] * sc;   // -log p[label]
  }
  __syncthreads();
  if (tid == 0) {
    blockloss[qb] = wl2[0] + wl2[1];
    st_flag(&lflag[qb], MAGIC);
  }

  if (qb == 0 && wave == 0) {              // final loss gather (block 80)
    for (int i = lane; i < 225; i += 64) spin_rlx(&lflag[i]);
    __builtin_amdgcn_fence(__ATOMIC_ACQUIRE, "agent");
    float s = 0.f;
    for (int i = lane; i < 225; i += 64) s += blockloss[i];
    for (int off = 32; off; off >>= 1) s += __shfl_down(s, off);
    if (lane == 0) out[2250] = s / 450.f;
  }
}

extern "C" void kernel_launch(void* const* d_in, const int* in_sizes, int n_in,
                              void* d_out, int out_size, void* d_ws, size_t ws_size,
                              hipStream_t stream) {
  const float* feat  = (const float*)d_in[0];
  const int*   label = (const int*)d_in[1];
  const float* scale = (const float*)d_in[2];
  const float* rvec  = (const float*)d_in[3];
  float* out = (float*)d_out;

  char* ws = (char*)d_ws;
  float*          partial   = (float*)ws;                       // 1,228,800 B
  unsigned short* G01h      = (unsigned short*)(ws + 1228800);  //    16,384 B
  unsigned short* G23h      = (unsigned short*)(ws + 1245184);  //    16,384 B
  unsigned short* G4h       = (unsigned short*)(ws + 1261568);  //     8,192 B
  float*          blockloss = (float*)(ws + 1269760);           //       900 B
  unsigned*       flags     = (unsigned*)(ws + 1270784);
  unsigned* gflag = flags;          // 75
  unsigned* sflag = flags + 80;     // 5
  unsigned* lflag = flags + 96;     // 225

  k_fused<<<dim3(305), dim3(256), 0, stream>>>(feat, label, scale, rvec, out,
                                               partial, G01h, G23h, G4h,
                                               blockloss, gflag, sflag, lflag);
}